// Round 9
// baseline (142.574 us; speedup 1.0000x reference)
//
#include <hip/hip_runtime.h>

// WaveletLoss: 3-level Haar DWT + soft-threshold + weighted mean-abs-diff.
// B=64, C=1, H=W=512.
// R8: hybrid read-path split. Per-CU outstanding-read-line limit (~40-56
// MSHRs) is the invariant wall across R0-R7; BW = L*128B/avg_latency, so the
// only lever left is latency. pred -> normal caching loads (67 MB fits L3,
// partially survives between dispatches, returns at L3-hit latency);
// target -> non-temporal loads (HBM stream, no allocate, keeps L3 clean for
// pred). Strip shape as R7: wave owns 8x256 strip, each load = contiguous
// 1024B row segment. 2048 blocks x 4 waves, 32 waves/CU.

#define IMG_W 512
#define N_BATCH 64

#define THR1 (50.0f / 255.0f)
#define THR2 (25.0f / 255.0f)
#define THR3 (12.5f / 255.0f)

#define NBLK 2048   // 2048 blocks * 4 waves = 8192 tiles of 8x256

typedef float v4f __attribute__((ext_vector_type(4)));

__device__ __forceinline__ float softthr(float x, float thr) {
    float m = fmaxf(fabsf(x) - thr, 0.0f);
    return copysignf(m, x);
}

__device__ __forceinline__ float detail_term(float p, float t, float thr) {
    return fabsf(softthr(p, thr) - softthr(t, thr));
}

__device__ __forceinline__ void haar_quad(float a, float b, float c, float d,
                                          float& cA, float& cH, float& cV, float& cD) {
    cA = 0.5f * (a + b + c + d);
    cH = 0.5f * (a + b - c - d);
    cV = 0.5f * (a - b + c - d);
    cD = 0.5f * (a - b - c + d);
}

__device__ __forceinline__ v4f ld4nt(const float* p) {
    return __builtin_nontemporal_load((const v4f*)p);
}
__device__ __forceinline__ v4f ld4(const float* p) {
    return *(const v4f*)p;
}

__global__ __launch_bounds__(256, 8)
void wavelet_main(const float* __restrict__ pred,
                  const float* __restrict__ target,
                  float* __restrict__ ws) {
    constexpr float W1 = 1.0f / (1.0f * 3.0f * (float)(N_BATCH * 256 * 256));
    constexpr float W2 = 1.0f / (2.0f * 3.0f * (float)(N_BATCH * 128 * 128));
    constexpr float W3 = 1.0f / (3.0f * 3.0f * (float)(N_BATCH * 64 * 64));

    const int T  = blockIdx.x * 4 + (threadIdx.x >> 6);   // tile id 0..8191
    const int li = threadIdx.x & 63;

    const int img   = T >> 7;
    const int rem   = T & 127;
    const int half  = rem & 1;
    const int strip = rem >> 1;               // 8-row strip 0..63

    const size_t off = (size_t)img * (512 * 512)
                     + (size_t)strip * 8 * IMG_W
                     + half * 256 + 4 * li;
    const float* pb = pred + off;
    const float* tb = target + off;

    // pred: normal caching loads (L3-friendly); target: non-temporal stream
    v4f P0 = ld4(pb);                   v4f P1 = ld4(pb + IMG_W);
    v4f P2 = ld4(pb + 2 * IMG_W);       v4f P3 = ld4(pb + 3 * IMG_W);
    v4f P4 = ld4(pb + 4 * IMG_W);       v4f P5 = ld4(pb + 5 * IMG_W);
    v4f P6 = ld4(pb + 6 * IMG_W);       v4f P7 = ld4(pb + 7 * IMG_W);
    v4f Q0 = ld4nt(tb);                 v4f Q1 = ld4nt(tb + IMG_W);
    v4f Q2 = ld4nt(tb + 2 * IMG_W);     v4f Q3 = ld4nt(tb + 3 * IMG_W);
    v4f Q4 = ld4nt(tb + 4 * IMG_W);     v4f Q5 = ld4nt(tb + 5 * IMG_W);
    v4f Q6 = ld4nt(tb + 6 * IMG_W);     v4f Q7 = ld4nt(tb + 7 * IMG_W);

    float s1 = 0.0f, s2 = 0.0f;
    float cA1p[4][2], cA1t[4][2];

    // ---- level 1: row-pairs (2rp, 2rp+1), two quads per pair (in-lane) ----
    {
        float cA, cH, cV, cD, cAt, cHt, cVt, cDt;

        #define L1_PAIR(a, b, qa, qb, rp)                                              \
        {                                                                              \
            haar_quad((a).x, (a).y, (b).x, (b).y, cA, cH, cV, cD);                     \
            haar_quad((qa).x, (qa).y, (qb).x, (qb).y, cAt, cHt, cVt, cDt);             \
            s1 += detail_term(cH, cHt, THR1) + detail_term(cV, cVt, THR1)              \
                + detail_term(cD, cDt, THR1);                                          \
            cA1p[rp][0] = cA; cA1t[rp][0] = cAt;                                       \
            haar_quad((a).z, (a).w, (b).z, (b).w, cA, cH, cV, cD);                     \
            haar_quad((qa).z, (qa).w, (qb).z, (qb).w, cAt, cHt, cVt, cDt);             \
            s1 += detail_term(cH, cHt, THR1) + detail_term(cV, cVt, THR1)              \
                + detail_term(cD, cDt, THR1);                                          \
            cA1p[rp][1] = cA; cA1t[rp][1] = cAt;                                       \
        }

        L1_PAIR(P0, P1, Q0, Q1, 0)
        L1_PAIR(P2, P3, Q2, Q3, 1)
        L1_PAIR(P4, P5, Q4, Q5, 2)
        L1_PAIR(P6, P7, Q6, Q7, 3)
        #undef L1_PAIR
    }

    // ---- level 2: two quads fully in-lane ----
    float cA2p[2], cA2t[2];
    {
        float cH, cV, cD, cHt, cVt, cDt;
        haar_quad(cA1p[0][0], cA1p[0][1], cA1p[1][0], cA1p[1][1], cA2p[0], cH, cV, cD);
        haar_quad(cA1t[0][0], cA1t[0][1], cA1t[1][0], cA1t[1][1], cA2t[0], cHt, cVt, cDt);
        s2 += detail_term(cH, cHt, THR2) + detail_term(cV, cVt, THR2) + detail_term(cD, cDt, THR2);
        haar_quad(cA1p[2][0], cA1p[2][1], cA1p[3][0], cA1p[3][1], cA2p[1], cH, cV, cD);
        haar_quad(cA1t[2][0], cA1t[2][1], cA1t[3][0], cA1t[3][1], cA2t[1], cHt, cVt, cDt);
        s2 += detail_term(cH, cHt, THR2) + detail_term(cV, cVt, THR2) + detail_term(cD, cDt, THR2);
    }

    // ---- level 3: horizontal neighbor via shfl_xor(1), vertical in-lane ----
    float s3;
    {
        const float bP = __shfl_xor(cA2p[0], 1);
        const float dP = __shfl_xor(cA2p[1], 1);
        const float bT = __shfl_xor(cA2t[0], 1);
        const float dT = __shfl_xor(cA2t[1], 1);
        float cA, cH, cV, cD, cAt, cHt, cVt, cDt;
        haar_quad(cA2p[0], bP, cA2p[1], dP, cA, cH, cV, cD);
        haar_quad(cA2t[0], bT, cA2t[1], dT, cAt, cHt, cVt, cDt);
        s3 = detail_term(cH, cHt, THR3) + detail_term(cV, cVt, THR3) + detail_term(cD, cDt, THR3);
    }
    const float w3 = (li & 1) ? 0.0f : W3;

    float acc = W1 * s1 + W2 * s2 + w3 * s3;

    // wave reduction (64 lanes)
    #pragma unroll
    for (int off = 32; off > 0; off >>= 1)
        acc += __shfl_down(acc, off, 64);

    __shared__ float wave_sums[4];
    const int lane_b = threadIdx.x & 63;
    const int wave_b = threadIdx.x >> 6;
    if (lane_b == 0) wave_sums[wave_b] = acc;
    __syncthreads();
    if (threadIdx.x == 0)
        ws[blockIdx.x] = wave_sums[0] + wave_sums[1] + wave_sums[2] + wave_sums[3];
}

__global__ __launch_bounds__(256)
void wavelet_reduce(const float* __restrict__ ws, float* __restrict__ out) {
    const int tidx = threadIdx.x;
    float v = 0.0f;
    #pragma unroll
    for (int k = 0; k < NBLK / 256; ++k)
        v += ws[tidx + k * 256];

    #pragma unroll
    for (int off = 32; off > 0; off >>= 1)
        v += __shfl_down(v, off, 64);

    __shared__ float wave_sums[4];
    const int lane = tidx & 63;
    const int wave = tidx >> 6;
    if (lane == 0) wave_sums[wave] = v;
    __syncthreads();
    if (tidx == 0)
        out[0] = wave_sums[0] + wave_sums[1] + wave_sums[2] + wave_sums[3];
}

extern "C" void kernel_launch(void* const* d_in, const int* in_sizes, int n_in,
                              void* d_out, int out_size, void* d_ws, size_t ws_size,
                              hipStream_t stream) {
    const float* pred   = (const float*)d_in[0];
    const float* target = (const float*)d_in[1];
    float* out = (float*)d_out;
    float* ws  = (float*)d_ws;   // NBLK floats = 8 KB

    wavelet_main<<<NBLK, 256, 0, stream>>>(pred, target, ws);
    wavelet_reduce<<<1, 256, 0, stream>>>(ws, out);
}

// Round 10
// 138.638 us; speedup vs baseline: 1.0284x; 1.0284x over previous
//
#include <hip/hip_runtime.h>

// WaveletLoss: 3-level Haar DWT + soft-threshold + weighted mean-abs-diff.
// B=64, C=1, H=W=512.
// R9: full L2-bypass probe. R7 structure (all-nt, wave owns 8x256 strip, each
// load = contiguous 1024B row segment) but the 16 stream loads are issued from
// ONE inline-asm block as `global_load_dwordx4 ... nt sc0 sc1` (system scope +
// non-temporal -> skip L2 allocate AND lookup) ending with s_waitcnt vmcnt(0).
// All results are asm outputs, so no use can be scheduled before the waitcnt.
// Row stride 2048B; offsets encoded as {-4096,-2048,0,2048} from bases at
// rows 2 and 6 (13-bit signed offset limit). __launch_bounds__(256,4).

#define IMG_W 512
#define N_BATCH 64

#define THR1 (50.0f / 255.0f)
#define THR2 (25.0f / 255.0f)
#define THR3 (12.5f / 255.0f)

#define NBLK 2048   // 2048 blocks * 4 waves = 8192 tiles of 8x256

typedef float v4f __attribute__((ext_vector_type(4)));

__device__ __forceinline__ float softthr(float x, float thr) {
    float m = fmaxf(fabsf(x) - thr, 0.0f);
    return copysignf(m, x);
}

__device__ __forceinline__ float detail_term(float p, float t, float thr) {
    return fabsf(softthr(p, thr) - softthr(t, thr));
}

__device__ __forceinline__ void haar_quad(float a, float b, float c, float d,
                                          float& cA, float& cH, float& cV, float& cD) {
    cA = 0.5f * (a + b + c + d);
    cH = 0.5f * (a + b - c - d);
    cV = 0.5f * (a - b + c - d);
    cD = 0.5f * (a - b - c + d);
}

__global__ __launch_bounds__(256, 4)
void wavelet_main(const float* __restrict__ pred,
                  const float* __restrict__ target,
                  float* __restrict__ ws) {
    constexpr float W1 = 1.0f / (1.0f * 3.0f * (float)(N_BATCH * 256 * 256));
    constexpr float W2 = 1.0f / (2.0f * 3.0f * (float)(N_BATCH * 128 * 128));
    constexpr float W3 = 1.0f / (3.0f * 3.0f * (float)(N_BATCH * 64 * 64));

    const int T  = blockIdx.x * 4 + (threadIdx.x >> 6);   // tile id 0..8191
    const int li = threadIdx.x & 63;

    const int img   = T >> 7;
    const int rem   = T & 127;
    const int half  = rem & 1;
    const int strip = rem >> 1;               // 8-row strip 0..63

    const size_t off = (size_t)img * (512 * 512)
                     + (size_t)strip * 8 * IMG_W
                     + half * 256 + 4 * li;
    // bases at rows 2 and 6 so offsets {-4096,-2048,0,2048} cover rows 0..7
    const float* pb2 = pred + off + 2 * IMG_W;
    const float* pb6 = pred + off + 6 * IMG_W;
    const float* tb2 = target + off + 2 * IMG_W;
    const float* tb6 = target + off + 6 * IMG_W;

    v4f P0, P1, P2, P3, P4, P5, P6, P7;
    v4f Q0, Q1, Q2, Q3, Q4, Q5, Q6, Q7;

    asm volatile(
        "global_load_dwordx4 %0,  %16, off offset:-4096 nt sc0 sc1\n\t"
        "global_load_dwordx4 %1,  %16, off offset:-2048 nt sc0 sc1\n\t"
        "global_load_dwordx4 %2,  %16, off nt sc0 sc1\n\t"
        "global_load_dwordx4 %3,  %16, off offset:2048 nt sc0 sc1\n\t"
        "global_load_dwordx4 %4,  %17, off offset:-4096 nt sc0 sc1\n\t"
        "global_load_dwordx4 %5,  %17, off offset:-2048 nt sc0 sc1\n\t"
        "global_load_dwordx4 %6,  %17, off nt sc0 sc1\n\t"
        "global_load_dwordx4 %7,  %17, off offset:2048 nt sc0 sc1\n\t"
        "global_load_dwordx4 %8,  %18, off offset:-4096 nt sc0 sc1\n\t"
        "global_load_dwordx4 %9,  %18, off offset:-2048 nt sc0 sc1\n\t"
        "global_load_dwordx4 %10, %18, off nt sc0 sc1\n\t"
        "global_load_dwordx4 %11, %18, off offset:2048 nt sc0 sc1\n\t"
        "global_load_dwordx4 %12, %19, off offset:-4096 nt sc0 sc1\n\t"
        "global_load_dwordx4 %13, %19, off offset:-2048 nt sc0 sc1\n\t"
        "global_load_dwordx4 %14, %19, off nt sc0 sc1\n\t"
        "global_load_dwordx4 %15, %19, off offset:2048 nt sc0 sc1\n\t"
        "s_waitcnt vmcnt(0)"
        : "=v"(P0), "=v"(P1), "=v"(P2), "=v"(P3),
          "=v"(P4), "=v"(P5), "=v"(P6), "=v"(P7),
          "=v"(Q0), "=v"(Q1), "=v"(Q2), "=v"(Q3),
          "=v"(Q4), "=v"(Q5), "=v"(Q6), "=v"(Q7)
        : "v"(pb2), "v"(pb6), "v"(tb2), "v"(tb6)
        : "memory");

    float s1 = 0.0f, s2 = 0.0f;
    float cA1p[4][2], cA1t[4][2];

    // ---- level 1: row-pairs (2rp, 2rp+1), two quads per pair (in-lane) ----
    {
        float cA, cH, cV, cD, cAt, cHt, cVt, cDt;

        #define L1_PAIR(a, b, qa, qb, rp)                                              \
        {                                                                              \
            haar_quad((a).x, (a).y, (b).x, (b).y, cA, cH, cV, cD);                     \
            haar_quad((qa).x, (qa).y, (qb).x, (qb).y, cAt, cHt, cVt, cDt);             \
            s1 += detail_term(cH, cHt, THR1) + detail_term(cV, cVt, THR1)              \
                + detail_term(cD, cDt, THR1);                                          \
            cA1p[rp][0] = cA; cA1t[rp][0] = cAt;                                       \
            haar_quad((a).z, (a).w, (b).z, (b).w, cA, cH, cV, cD);                     \
            haar_quad((qa).z, (qa).w, (qb).z, (qb).w, cAt, cHt, cVt, cDt);             \
            s1 += detail_term(cH, cHt, THR1) + detail_term(cV, cVt, THR1)              \
                + detail_term(cD, cDt, THR1);                                          \
            cA1p[rp][1] = cA; cA1t[rp][1] = cAt;                                       \
        }

        L1_PAIR(P0, P1, Q0, Q1, 0)
        L1_PAIR(P2, P3, Q2, Q3, 1)
        L1_PAIR(P4, P5, Q4, Q5, 2)
        L1_PAIR(P6, P7, Q6, Q7, 3)
        #undef L1_PAIR
    }

    // ---- level 2: two quads fully in-lane ----
    float cA2p[2], cA2t[2];
    {
        float cH, cV, cD, cHt, cVt, cDt;
        haar_quad(cA1p[0][0], cA1p[0][1], cA1p[1][0], cA1p[1][1], cA2p[0], cH, cV, cD);
        haar_quad(cA1t[0][0], cA1t[0][1], cA1t[1][0], cA1t[1][1], cA2t[0], cHt, cVt, cDt);
        s2 += detail_term(cH, cHt, THR2) + detail_term(cV, cVt, THR2) + detail_term(cD, cDt, THR2);
        haar_quad(cA1p[2][0], cA1p[2][1], cA1p[3][0], cA1p[3][1], cA2p[1], cH, cV, cD);
        haar_quad(cA1t[2][0], cA1t[2][1], cA1t[3][0], cA1t[3][1], cA2t[1], cHt, cVt, cDt);
        s2 += detail_term(cH, cHt, THR2) + detail_term(cV, cVt, THR2) + detail_term(cD, cDt, THR2);
    }

    // ---- level 3: horizontal neighbor via shfl_xor(1), vertical in-lane ----
    float s3;
    {
        const float bP = __shfl_xor(cA2p[0], 1);
        const float dP = __shfl_xor(cA2p[1], 1);
        const float bT = __shfl_xor(cA2t[0], 1);
        const float dT = __shfl_xor(cA2t[1], 1);
        float cA, cH, cV, cD, cAt, cHt, cVt, cDt;
        haar_quad(cA2p[0], bP, cA2p[1], dP, cA, cH, cV, cD);
        haar_quad(cA2t[0], bT, cA2t[1], dT, cAt, cHt, cVt, cDt);
        s3 = detail_term(cH, cHt, THR3) + detail_term(cV, cVt, THR3) + detail_term(cD, cDt, THR3);
    }
    const float w3 = (li & 1) ? 0.0f : W3;

    float acc = W1 * s1 + W2 * s2 + w3 * s3;

    // wave reduction (64 lanes)
    #pragma unroll
    for (int off2 = 32; off2 > 0; off2 >>= 1)
        acc += __shfl_down(acc, off2, 64);

    __shared__ float wave_sums[4];
    const int lane_b = threadIdx.x & 63;
    const int wave_b = threadIdx.x >> 6;
    if (lane_b == 0) wave_sums[wave_b] = acc;
    __syncthreads();
    if (threadIdx.x == 0)
        ws[blockIdx.x] = wave_sums[0] + wave_sums[1] + wave_sums[2] + wave_sums[3];
}

__global__ __launch_bounds__(256)
void wavelet_reduce(const float* __restrict__ ws, float* __restrict__ out) {
    const int tidx = threadIdx.x;
    float v = 0.0f;
    #pragma unroll
    for (int k = 0; k < NBLK / 256; ++k)
        v += ws[tidx + k * 256];

    #pragma unroll
    for (int off = 32; off > 0; off >>= 1)
        v += __shfl_down(v, off, 64);

    __shared__ float wave_sums[4];
    const int lane = tidx & 63;
    const int wave = tidx >> 6;
    if (lane == 0) wave_sums[wave] = v;
    __syncthreads();
    if (tidx == 0)
        out[0] = wave_sums[0] + wave_sums[1] + wave_sums[2] + wave_sums[3];
}

extern "C" void kernel_launch(void* const* d_in, const int* in_sizes, int n_in,
                              void* d_out, int out_size, void* d_ws, size_t ws_size,
                              hipStream_t stream) {
    const float* pred   = (const float*)d_in[0];
    const float* target = (const float*)d_in[1];
    float* out = (float*)d_out;
    float* ws  = (float*)d_ws;   // NBLK floats = 8 KB

    wavelet_main<<<NBLK, 256, 0, stream>>>(pred, target, ws);
    wavelet_reduce<<<1, 256, 0, stream>>>(ws, out);
}